// Round 14
// baseline (125.778 us; speedup 1.0000x reference)
//
#include <hip/hip_runtime.h>

typedef __bf16 bf16x8 __attribute__((ext_vector_type(8)));
typedef float f32x4 __attribute__((ext_vector_type(4)));
typedef unsigned short ushort8u __attribute__((ext_vector_type(8)));
typedef unsigned short ushort_t;

#define NB 8
#define LQ 128
#define LP 128
#define HH 256
#define HID 128

__device__ __forceinline__ float bf2f(unsigned short u) {
  union { unsigned int i; float f; } v; v.i = ((unsigned int)u) << 16; return v.f;
}
__device__ __forceinline__ unsigned short f2bf(float f) {
  union { float fl; unsigned int i; } v; v.fl = f;
  unsigned int r = v.i + 0x7FFFu + ((v.i >> 16) & 1u);
  return (unsigned short)(r >> 16);
}
// tanh(x) = 1 - 2/(e^{2x}+1); e^{2x} = 2^(x*2/ln2). NaN-free at +/-inf, no clamp.
__device__ __forceinline__ float tanh_fast(float x) {
  float t = __builtin_amdgcn_exp2f(x * 2.88539008178f);
  return 1.f - 2.f * __builtin_amdgcn_rcpf(t + 1.f);
}

// ---------------- Kernel A: f32 projections + bf16 copies (R13-verbatim) ----------------
__global__ __launch_bounds__(256) void kernelA(
    const float* __restrict__ hq, const float* __restrict__ hp,
    const float* __restrict__ mask_hp, const float* __restrict__ Wc,
    const float* __restrict__ Wm, const float* __restrict__ Wb,
    const float* __restrict__ bb, const float* __restrict__ Wd,
    float* __restrict__ aq, float* __restrict__ apc, float* __restrict__ qm,
    float* __restrict__ pm, float* __restrict__ hpb,
    ushort_t* __restrict__ hq_bf, ushort_t* __restrict__ hqT_bf, ushort_t* __restrict__ wdt)
{
  const int blk = blockIdx.x;
  const int typ = blk >> 8;
  const int sub = blk & 255;
  const int b = sub >> 5;
  const int i0 = (sub & 31) * 4;
  const int t = threadIdx.x;
  __shared__ __align__(16) float row[4][256];
  const float* src = (typ == 0) ? hq : hp;
  #pragma unroll
  for (int r = 0; r < 4; ++r) {
    float v = src[(b * 128 + i0 + r) * 256 + t];
    row[r][t] = v;
    if (typ == 0) {
      unsigned short bv = f2bf(v);
      hq_bf[(b * 128 + i0 + r) * 256 + t] = bv;
      hqT_bf[(b * 256 + t) * 128 + i0 + r] = bv;
    }
  }
  if (typ == 0 && sub < 128) {
    int flat = sub * 256 + t;                       // wdt[k][h] = bf16(Wd[h][k])
    wdt[flat] = f2bf(Wd[(flat & 255) * 128 + (flat >> 8)]);
  }
  __syncthreads();
  float acc[4] = {0.f,0.f,0.f,0.f};
  if (typ == 2) {
    const float* Wp = Wb + t;
    #pragma unroll 4
    for (int h = 0; h < 256; h += 4) {
      float w0 = Wp[(h+0)*256], w1 = Wp[(h+1)*256], w2 = Wp[(h+2)*256], w3 = Wp[(h+3)*256];
      #pragma unroll
      for (int r = 0; r < 4; ++r) {
        const float4 rv = *(const float4*)&row[r][h];
        acc[r] = fmaf(rv.x, w0, fmaf(rv.y, w1, fmaf(rv.z, w2, fmaf(rv.w, w3, acc[r]))));
      }
    }
    float bias = bb[t];
    #pragma unroll
    for (int r = 0; r < 4; ++r) {
      float mk = mask_hp[b * 128 + i0 + r];
      hpb[(b * 128 + i0 + r) * 256 + t] = (acc[r] + bias) * mk;
    }
  } else {
    const int c = t & 127;
    const float* Wp;
    float* outp;
    if (typ == 0) { Wp = (t < 128) ? (Wc + c) : (Wm + c);        outp = (t < 128) ? aq  : qm; }
    else          { Wp = (t < 128) ? (Wc + 32768 + c) : (Wm + c); outp = (t < 128) ? apc : pm; }
    #pragma unroll 4
    for (int h = 0; h < 256; h += 4) {
      float w0 = Wp[(h+0)*128], w1 = Wp[(h+1)*128], w2 = Wp[(h+2)*128], w3 = Wp[(h+3)*128];
      #pragma unroll
      for (int r = 0; r < 4; ++r) {
        const float4 rv = *(const float4*)&row[r][h];
        acc[r] = fmaf(rv.x, w0, fmaf(rv.y, w1, fmaf(rv.z, w2, fmaf(rv.w, w3, acc[r]))));
      }
    }
    #pragma unroll
    for (int r = 0; r < 4; ++r)
      outp[(b * 128 + i0 + r) * 128 + c] = acc[r];
  }
}

// ---------------- Kernel S: all four score matrices, block-typed ----------------
// bid < 512  : B-type  -> s_d via MFMA, j-pair per block (j = (bid&63)*2 + jj, b = bid>>6)
// bid < 1024 : T-type  -> s_c, s_m tanh tiles (R4 body)
// else       : SB-type -> s_b f32 GEMM (R4 body)
__global__ __launch_bounds__(256, 2) void kernelS(
    const float* __restrict__ hq, const float* __restrict__ hp, const float* __restrict__ hpb,
    const float* __restrict__ aq, const float* __restrict__ apc,
    const float* __restrict__ qm, const float* __restrict__ pm,
    const float* __restrict__ bc, const float* __restrict__ vc,
    const float* __restrict__ bm, const float* __restrict__ vm,
    const float* __restrict__ bd, const float* __restrict__ vd,
    const ushort_t* __restrict__ hq_bf, const ushort_t* __restrict__ wdt,
    float* __restrict__ s_c, float* __restrict__ s_d,
    float* __restrict__ s_m, float* __restrict__ s_b)
{
  __shared__ __align__(16) char smem[65536];
  const int bid = blockIdx.x;
  const int t = threadIdx.x;

  if (bid < 512) {
    // ---------- B-type: s_d[b][j][i] = sum_k vd[k] tanh( (hq @ diag(hp_j) @ Wd)[i,k] + bd[k] )
    ushort_t* X = (ushort_t*)smem;   // 64KB bf16 [k 0..127][h 0..255], XOR-swizzled
    const int j0 = (bid & 63) * 2, b = bid >> 6;
    const int lane = t & 63, w = t >> 6;
    const int lr = lane & 15, lh = lane >> 4;
    const int h0 = (t * 8) & 255;
    const int kbase = t >> 5;
    // --- prefetch A row-pair into registers (64 VGPR): rows w*32+lr, w*32+16+lr  (j-independent)
    const ushort_t* Ab = hq_bf + (b * LQ) * HH;
    const ushort_t* r0 = Ab + (w * 32 + lr) * HH;
    const ushort_t* r1 = Ab + (w * 32 + 16 + lr) * HH;
    bf16x8 areg0[8], areg1[8];
    #pragma unroll
    for (int s = 0; s < 8; ++s) {
      areg0[s] = *(const bf16x8*)(r0 + s * 32 + lh * 8);
      areg1[s] = *(const bf16x8*)(r1 + s * 32 + lh * 8);
    }
    // --- vd/bd constants (j-independent)
    float vdk[8], bdk[8];
    #pragma unroll
    for (int nt = 0; nt < 8; ++nt) {
      const int k = nt * 16 + lr;
      vdk[nt] = vd[k]; bdk[nt] = bd[k];
    }
    for (int jj = 0; jj < 2; ++jj) {
      const int j = j0 + jj;
      // --- hp slice for this thread's h0
      const float* hprow = hp + (b * LP + j) * HH + h0;
      float hpv[8];
      {
        float4 h4a = *(const float4*)(hprow);
        float4 h4b = *(const float4*)(hprow + 4);
        hpv[0]=h4a.x; hpv[1]=h4a.y; hpv[2]=h4a.z; hpv[3]=h4a.w;
        hpv[4]=h4b.x; hpv[5]=h4b.y; hpv[6]=h4b.z; hpv[7]=h4b.w;
      }
      // --- build full X: X[k][h] = bf16( wdt[k][h] * hp[b,j,h] ), k = rep*8+kbase
      #pragma unroll
      for (int rep = 0; rep < 16; ++rep) {
        const int kl = rep * 8 + kbase;
        ushort8u wv = *(const ushort8u*)(wdt + kl * HH + h0);
        bf16x8 xv;
        #pragma unroll
        for (int e = 0; e < 8; ++e) xv[e] = (__bf16)(bf2f(wv[e]) * hpv[e]);
        const int off = (kl * 512 + h0 * 2) ^ ((kl & 7) << 4);
        *(bf16x8*)((char*)X + off) = xv;
      }
      f32x4 acc[2][8];
      #pragma unroll
      for (int a1 = 0; a1 < 2; ++a1)
        #pragma unroll
        for (int a2 = 0; a2 < 8; ++a2)
          acc[a1][a2] = (f32x4){0.f, 0.f, 0.f, 0.f};
      __syncthreads();
      // --- 128 MFMAs per wave, A from registers, B from LDS
      #pragma unroll
      for (int s = 0; s < 8; ++s) {
        #pragma unroll
        for (int nt = 0; nt < 8; ++nt) {
          const int cl = nt * 16 + lr;
          const int off = (cl * 512 + s * 64 + lh * 16) ^ ((cl & 7) << 4);
          bf16x8 bv = *(const bf16x8*)((const char*)X + off);
          acc[0][nt] = __builtin_amdgcn_mfma_f32_16x16x32_bf16(areg0[s], bv, acc[0][nt], 0, 0, 0);
          acc[1][nt] = __builtin_amdgcn_mfma_f32_16x16x32_bf16(areg1[s], bv, acc[1][nt], 0, 0, 0);
        }
      }
      // --- epilogue
      const int jrow = (b * LP + j) * LQ;
      #pragma unroll
      for (int rt = 0; rt < 2; ++rt) {
        #pragma unroll
        for (int q = 0; q < 4; ++q) {
          const int i = w * 32 + rt * 16 + lh * 4 + q;
          float sd = 0.f;
          #pragma unroll
          for (int nt = 0; nt < 8; ++nt)
            sd += vdk[nt] * tanh_fast(acc[rt][nt][q] + bdk[nt]);
          #pragma unroll
          for (int d = 1; d < 16; d <<= 1) sd += __shfl_xor(sd, d);
          if (lr == 0) s_d[jrow + i] = sd;
        }
      }
      // protect X from next iteration's overwrite (all reads done)
      __syncthreads();
    }
  } else if (bid < 1024) {
    // ---------- T-type: s_c / s_m, tile 16i x 16j (R4 body)
    const int sub = bid - 512;
    const int it = sub & 7, jt = (sub >> 3) & 7, b = sub >> 6;
    float (*aq_s)[132] = (float(*)[132])(smem);
    float (*qm_s)[132] = (float(*)[132])(smem + 8448);
    float (*ap_s)[132] = (float(*)[132])(smem + 16896);
    float (*pm_s)[132] = (float(*)[132])(smem + 25344);
    float* vc_s = (float*)(smem + 33792);
    float* vm_s = (float*)(smem + 34304);
    const int lr_ = t >> 5;           // 0..7
    const int lc_ = (t & 31) * 4;     // 0..124
    #pragma unroll
    for (int rr = 0; rr < 2; ++rr) {
      const int r = lr_ + rr * 8;
      const int qrow = (b * LQ + it * 16 + r) * HID + lc_;
      const int prow = (b * LP + jt * 16 + r) * HID + lc_;
      *(float4*)&aq_s[r][lc_] = *(const float4*)&aq[qrow];
      *(float4*)&qm_s[r][lc_] = *(const float4*)&qm[qrow];
      float4 a4 = *(const float4*)&apc[prow];
      float4 c4 = *(const float4*)&bc[lc_];
      ap_s[r][lc_+0] = a4.x + c4.x; ap_s[r][lc_+1] = a4.y + c4.y;
      ap_s[r][lc_+2] = a4.z + c4.z; ap_s[r][lc_+3] = a4.w + c4.w;
      float4 p4 = *(const float4*)&pm[prow];
      float4 m4 = *(const float4*)&bm[lc_];
      pm_s[r][lc_+0] = m4.x - p4.x; pm_s[r][lc_+1] = m4.y - p4.y;
      pm_s[r][lc_+2] = m4.z - p4.z; pm_s[r][lc_+3] = m4.w - p4.w;
    }
    if (t < 128) { vc_s[t] = vc[t]; vm_s[t] = vm[t]; }
    __syncthreads();
    const int i = t & 15, j = t >> 4;
    float sc = 0.f, sm = 0.f;
    #pragma unroll 4
    for (int k = 0; k < 128; k += 4) {
      float4 av = *(const float4*)&aq_s[i][k];
      float4 pv = *(const float4*)&ap_s[j][k];
      float4 qv = *(const float4*)&qm_s[i][k];
      float4 mv = *(const float4*)&pm_s[j][k];
      float4 vcv = *(const float4*)&vc_s[k];
      float4 vmv = *(const float4*)&vm_s[k];
      sc += vcv.x * tanh_fast(av.x + pv.x) + vcv.y * tanh_fast(av.y + pv.y)
          + vcv.z * tanh_fast(av.z + pv.z) + vcv.w * tanh_fast(av.w + pv.w);
      sm += vmv.x * tanh_fast(qv.x + mv.x) + vmv.y * tanh_fast(qv.y + mv.y)
          + vmv.z * tanh_fast(qv.z + mv.z) + vmv.w * tanh_fast(qv.w + mv.w);
    }
    const int orow = (b * LP + jt * 16 + j) * LQ + it * 16 + i;
    s_c[orow] = sc;
    s_m[orow] = sm;
  } else {
    // ---------- SB-type: s_b[b][j][i] = hpb[b,j,:] . hq[b,i,:]  (R4 body)
    const int sub = bid - 1024;       // 0..127
    const int b = sub >> 4;
    const int jt = (sub & 15) >> 2, it = sub & 3;
    float (*At)[65] = (float(*)[65])(smem);
    float (*Bt)[65] = (float(*)[65])(smem + 32 * 65 * 4);
    float acc[4] = {0.f,0.f,0.f,0.f};
    const int sr = t >> 3, c0 = (t & 7) * 8;
    const int tj = t >> 5, ti = t & 31;
    for (int kk = 0; kk < 256; kk += 64) {
      #pragma unroll
      for (int e = 0; e < 8; ++e) {
        At[sr][c0 + e] = hpb[(b * LP + jt * 32 + sr) * HH + kk + c0 + e];
        Bt[sr][c0 + e] = hq [(b * LQ + it * 32 + sr) * HH + kk + c0 + e];
      }
      __syncthreads();
      #pragma unroll
      for (int k = 0; k < 64; ++k) {
        const float bv = Bt[ti][k];
        #pragma unroll
        for (int s2 = 0; s2 < 4; ++s2) acc[s2] = fmaf(At[tj + 8 * s2][k], bv, acc[s2]);
      }
      __syncthreads();
    }
    #pragma unroll
    for (int s2 = 0; s2 < 4; ++s2)
      s_b[(b * LP + jt * 32 + tj + 8 * s2) * LQ + it * 32 + ti] = acc[s2];
  }
}

// ---------------- Kernel C: softmax over i (per (b,j,attn) column) + attend via MFMA (R13-verbatim) ----------------
__global__ __launch_bounds__(256) void kernelC(
    const float* __restrict__ s_c, const float* __restrict__ s_d, const float* __restrict__ s_m,
    const float* __restrict__ s_b, const float* __restrict__ mask_hq, const float* __restrict__ mask_hp,
    const ushort_t* __restrict__ hqT_bf, float* __restrict__ out)
{
  const int b = blockIdx.y, j0 = blockIdx.x * 4;
  const int t = threadIdx.x;
  const int lane = t & 63, w = t >> 6;
  const int lr = lane & 15, lh = lane >> 4;
  __shared__ __align__(16) ushort_t a_s[16 * 128];   // bf16 softmax weights [c][i], c = attn*4+jj
  const int c = w * 4 + lh;
  const int attn = c >> 2, jj = c & 3;
  const float* sbase = (attn == 0) ? s_c : (attn == 1) ? s_d : (attn == 2) ? s_m : s_b;
  const int j = j0 + jj;
  const float mp = mask_hp[b * LP + j];
  float v[8];
  #pragma unroll
  for (int e = 0; e < 8; ++e) {
    const int i = e * 16 + lr;
    float sv = sbase[(b * LP + j) * LQ + i];
    float mq = mask_hq[b * LQ + i];
    if (mq * mp == 0.f) sv -= 10000.f;
    v[e] = sv;
  }
  float m = v[0];
  #pragma unroll
  for (int e = 1; e < 8; ++e) m = fmaxf(m, v[e]);
  #pragma unroll
  for (int d = 1; d < 16; d <<= 1) m = fmaxf(m, __shfl_xor(m, d));
  float sum = 0.f;
  #pragma unroll
  for (int e = 0; e < 8; ++e) { v[e] = __expf(v[e] - m); sum += v[e]; }
  #pragma unroll
  for (int d = 1; d < 16; d <<= 1) sum += __shfl_xor(sum, d);
  const float rs = __fdividef(1.f, sum);
  #pragma unroll
  for (int e = 0; e < 8; ++e) a_s[c * 128 + e * 16 + lr] = f2bf(v[e] * rs);
  __syncthreads();
  // out[c][h] = sum_i a[c][i] * hq[b,i,h] ; A = a_s (M=16 c), B = hqT_bf (N=h), K=i=128
  f32x4 acc[4];
  #pragma unroll
  for (int nt = 0; nt < 4; ++nt) acc[nt] = (f32x4){0.f, 0.f, 0.f, 0.f};
  #pragma unroll
  for (int ks = 0; ks < 4; ++ks) {
    bf16x8 av = *(const bf16x8*)(a_s + lr * 128 + ks * 32 + lh * 8);
    #pragma unroll
    for (int nt = 0; nt < 4; ++nt) {
      const int h = w * 64 + nt * 16 + lr;
      bf16x8 bv = *(const bf16x8*)(hqT_bf + (b * HH + h) * LQ + ks * 32 + lh * 8);
      acc[nt] = __builtin_amdgcn_mfma_f32_16x16x32_bf16(av, bv, acc[nt], 0, 0, 0);
    }
  }
  #pragma unroll
  for (int nt = 0; nt < 4; ++nt) {
    const int h = w * 64 + nt * 16 + lr;
    #pragma unroll
    for (int q = 0; q < 4; ++q) {
      const int c2 = lh * 4 + q;
      out[(b * LP + j0 + (c2 & 3)) * (4 * HH) + (c2 >> 2) * HH + h] = acc[nt][q];
    }
  }
}

extern "C" void kernel_launch(void* const* d_in, const int* in_sizes, int n_in,
                              void* d_out, int out_size, void* d_ws, size_t ws_size,
                              hipStream_t stream) {
  const float* hq      = (const float*)d_in[0];
  const float* hp      = (const float*)d_in[1];
  const float* mask_hq = (const float*)d_in[2];
  const float* mask_hp = (const float*)d_in[3];
  const float* Wc      = (const float*)d_in[4];
  const float* bc      = (const float*)d_in[5];
  const float* vc      = (const float*)d_in[6];
  const float* Wd      = (const float*)d_in[7];
  const float* bd      = (const float*)d_in[8];
  const float* vd      = (const float*)d_in[9];
  const float* Wm      = (const float*)d_in[10];
  const float* bm      = (const float*)d_in[11];
  const float* vm      = (const float*)d_in[12];
  const float* Wb      = (const float*)d_in[13];
  const float* bb      = (const float*)d_in[14];

  float* ws = (float*)d_ws;
  float* aq    = ws + 0;        // B*LQ*HID
  float* apc   = ws + 131072;   // B*LP*HID
  float* qm    = ws + 262144;   // B*LQ*HID
  float* pm    = ws + 393216;   // B*LP*HID
  float* hpb   = ws + 524288;   // B*LP*H
  float* s_c   = ws + 786432;   // B*LP*LQ  (stored [b][j][i])
  float* s_d   = ws + 917504;
  float* s_m   = ws + 1048576;
  float* s_b   = ws + 1179648;
  ushort_t* hq_bf = (ushort_t*)(ws + 1310720);  // B*LQ*H bf16
  ushort_t* wdt   = (ushort_t*)(ws + 1441792);  // HID*H bf16 (Wd transposed)
  ushort_t* hqT   = (ushort_t*)(ws + 1458176);  // B*H*LQ bf16 (hq transposed)

  kernelA<<<768, 256, 0, stream>>>(hq, hp, mask_hp, Wc, Wm, Wb, bb, Wd,
                                   aq, apc, qm, pm, hpb, hq_bf, hqT, wdt);
  kernelS<<<1152, 256, 0, stream>>>(hq, hp, hpb, aq, apc, qm, pm,
                                    bc, vc, bm, vm, bd, vd, hq_bf, wdt,
                                    s_c, s_d, s_m, s_b);
  kernelC<<<dim3(32, 8), 256, 0, stream>>>(s_c, s_d, s_m, s_b, mask_hq, mask_hp, hqT, (float*)d_out);
}

// Round 15
// 66.603 us; speedup vs baseline: 1.8885x; 1.8885x over previous
//
#include <hip/hip_runtime.h>

typedef __bf16 bf16x8 __attribute__((ext_vector_type(8)));
typedef float f32x4 __attribute__((ext_vector_type(4)));
typedef unsigned short ushort8u __attribute__((ext_vector_type(8)));
typedef unsigned short ushort_t;

#define NB 8
#define LQ 128
#define LP 128
#define HH 256
#define HID 128

__device__ __forceinline__ float bf2f(unsigned short u) {
  union { unsigned int i; float f; } v; v.i = ((unsigned int)u) << 16; return v.f;
}
__device__ __forceinline__ unsigned short f2bf(float f) {
  union { float fl; unsigned int i; } v; v.fl = f;
  unsigned int r = v.i + 0x7FFFu + ((v.i >> 16) & 1u);
  return (unsigned short)(r >> 16);
}
// tanh(x) = 1 - 2/(e^{2x}+1); e^{2x} = 2^(x*2/ln2). NaN-free at +/-inf, no clamp.
__device__ __forceinline__ float tanh_fast(float x) {
  float t = __builtin_amdgcn_exp2f(x * 2.88539008178f);
  return 1.f - 2.f * __builtin_amdgcn_rcpf(t + 1.f);
}

// ---------------- Kernel A: f32 projections + bf16 copies ----------------
__global__ __launch_bounds__(256) void kernelA(
    const float* __restrict__ hq, const float* __restrict__ hp,
    const float* __restrict__ mask_hp, const float* __restrict__ Wc,
    const float* __restrict__ Wm, const float* __restrict__ Wb,
    const float* __restrict__ bb, const float* __restrict__ Wd,
    float* __restrict__ aq, float* __restrict__ apc, float* __restrict__ qm,
    float* __restrict__ pm, float* __restrict__ hpb,
    ushort_t* __restrict__ hq_bf, ushort_t* __restrict__ hqT_bf, ushort_t* __restrict__ wdt)
{
  const int blk = blockIdx.x;
  const int typ = blk >> 8;
  const int sub = blk & 255;
  const int b = sub >> 5;
  const int i0 = (sub & 31) * 4;
  const int t = threadIdx.x;
  __shared__ __align__(16) float row[4][256];
  const float* src = (typ == 0) ? hq : hp;
  #pragma unroll
  for (int r = 0; r < 4; ++r) {
    float v = src[(b * 128 + i0 + r) * 256 + t];
    row[r][t] = v;
    if (typ == 0) {
      unsigned short bv = f2bf(v);
      hq_bf[(b * 128 + i0 + r) * 256 + t] = bv;
      hqT_bf[(b * 256 + t) * 128 + i0 + r] = bv;
    }
  }
  if (typ == 0 && sub < 128) {
    int flat = sub * 256 + t;                       // wdt[k][h] = bf16(Wd[h][k])
    wdt[flat] = f2bf(Wd[(flat & 255) * 128 + (flat >> 8)]);
  }
  __syncthreads();
  float acc[4] = {0.f,0.f,0.f,0.f};
  if (typ == 2) {
    const float* Wp = Wb + t;
    #pragma unroll 4
    for (int h = 0; h < 256; h += 4) {
      float w0 = Wp[(h+0)*256], w1 = Wp[(h+1)*256], w2 = Wp[(h+2)*256], w3 = Wp[(h+3)*256];
      #pragma unroll
      for (int r = 0; r < 4; ++r) {
        const float4 rv = *(const float4*)&row[r][h];
        acc[r] = fmaf(rv.x, w0, fmaf(rv.y, w1, fmaf(rv.z, w2, fmaf(rv.w, w3, acc[r]))));
      }
    }
    float bias = bb[t];
    #pragma unroll
    for (int r = 0; r < 4; ++r) {
      float mk = mask_hp[b * 128 + i0 + r];
      hpb[(b * 128 + i0 + r) * 256 + t] = (acc[r] + bias) * mk;
    }
  } else {
    const int c = t & 127;
    const float* Wp;
    float* outp;
    if (typ == 0) { Wp = (t < 128) ? (Wc + c) : (Wm + c);        outp = (t < 128) ? aq  : qm; }
    else          { Wp = (t < 128) ? (Wc + 32768 + c) : (Wm + c); outp = (t < 128) ? apc : pm; }
    #pragma unroll 4
    for (int h = 0; h < 256; h += 4) {
      float w0 = Wp[(h+0)*128], w1 = Wp[(h+1)*128], w2 = Wp[(h+2)*128], w3 = Wp[(h+3)*128];
      #pragma unroll
      for (int r = 0; r < 4; ++r) {
        const float4 rv = *(const float4*)&row[r][h];
        acc[r] = fmaf(rv.x, w0, fmaf(rv.y, w1, fmaf(rv.z, w2, fmaf(rv.w, w3, acc[r]))));
      }
    }
    #pragma unroll
    for (int r = 0; r < 4; ++r)
      outp[(b * 128 + i0 + r) * 128 + c] = acc[r];
  }
}

// ---------------- Kernel S: all four score matrices, block-typed ----------------
// bid < 1024 : B-type  -> s_d via MFMA  (j = bid&127, b = bid>>7)
// bid < 1536 : T-type  -> s_c, s_m tanh tiles
// else       : SB-type -> s_b f32 GEMM
__global__ __launch_bounds__(256, 2) void kernelS(
    const float* __restrict__ hq, const float* __restrict__ hp, const float* __restrict__ hpb,
    const float* __restrict__ aq, const float* __restrict__ apc,
    const float* __restrict__ qm, const float* __restrict__ pm,
    const float* __restrict__ bc, const float* __restrict__ vc,
    const float* __restrict__ bm, const float* __restrict__ vm,
    const float* __restrict__ bd, const float* __restrict__ vd,
    const ushort_t* __restrict__ hq_bf, const ushort_t* __restrict__ wdt,
    float* __restrict__ s_c, float* __restrict__ s_d,
    float* __restrict__ s_m, float* __restrict__ s_b)
{
  __shared__ __align__(16) char smem[65536];
  const int bid = blockIdx.x;
  const int t = threadIdx.x;

  if (bid < 1024) {
    // ---------- B-type: s_d[b][j][i] = sum_k vd[k] tanh( (hq @ diag(hp_j) @ Wd)[i,k] + bd[k] )
    ushort_t* X = (ushort_t*)smem;   // 64KB bf16 [k 0..127][h 0..255], XOR-swizzled
    const int j = bid & 127, b = bid >> 7;
    const int lane = t & 63, w = t >> 6;
    const int lr = lane & 15, lh = lane >> 4;
    const int h0 = (t * 8) & 255;
    const int kbase = t >> 5;
    // --- prefetch A row-pair into registers (64 VGPR): rows w*32+lr, w*32+16+lr
    const ushort_t* Ab = hq_bf + (b * LQ) * HH;
    const ushort_t* r0 = Ab + (w * 32 + lr) * HH;
    const ushort_t* r1 = Ab + (w * 32 + 16 + lr) * HH;
    bf16x8 areg0[8], areg1[8];
    #pragma unroll
    for (int s = 0; s < 8; ++s) {
      areg0[s] = *(const bf16x8*)(r0 + s * 32 + lh * 8);
      areg1[s] = *(const bf16x8*)(r1 + s * 32 + lh * 8);
    }
    // --- hp slice for this thread's h0
    const float* hprow = hp + (b * LP + j) * HH + h0;
    float hpv[8];
    {
      float4 h4a = *(const float4*)(hprow);
      float4 h4b = *(const float4*)(hprow + 4);
      hpv[0]=h4a.x; hpv[1]=h4a.y; hpv[2]=h4a.z; hpv[3]=h4a.w;
      hpv[4]=h4b.x; hpv[5]=h4b.y; hpv[6]=h4b.z; hpv[7]=h4b.w;
    }
    // --- build full X: X[k][h] = bf16( wdt[k][h] * hp[b,j,h] ), k = rep*8+kbase
    #pragma unroll
    for (int rep = 0; rep < 16; ++rep) {
      const int kl = rep * 8 + kbase;
      ushort8u wv = *(const ushort8u*)(wdt + kl * HH + h0);
      bf16x8 xv;
      #pragma unroll
      for (int e = 0; e < 8; ++e) xv[e] = (__bf16)(bf2f(wv[e]) * hpv[e]);
      const int off = (kl * 512 + h0 * 2) ^ ((kl & 7) << 4);
      *(bf16x8*)((char*)X + off) = xv;
    }
    f32x4 acc[2][8];
    #pragma unroll
    for (int a1 = 0; a1 < 2; ++a1)
      #pragma unroll
      for (int a2 = 0; a2 < 8; ++a2)
        acc[a1][a2] = (f32x4){0.f, 0.f, 0.f, 0.f};
    __syncthreads();
    // --- 128 MFMAs per wave, A from registers, B from LDS
    #pragma unroll
    for (int s = 0; s < 8; ++s) {
      #pragma unroll
      for (int nt = 0; nt < 8; ++nt) {
        const int cl = nt * 16 + lr;
        const int off = (cl * 512 + s * 64 + lh * 16) ^ ((cl & 7) << 4);
        bf16x8 bv = *(const bf16x8*)((const char*)X + off);
        acc[0][nt] = __builtin_amdgcn_mfma_f32_16x16x32_bf16(areg0[s], bv, acc[0][nt], 0, 0, 0);
        acc[1][nt] = __builtin_amdgcn_mfma_f32_16x16x32_bf16(areg1[s], bv, acc[1][nt], 0, 0, 0);
      }
    }
    // --- epilogue
    float vdk[8], bdk[8];
    #pragma unroll
    for (int nt = 0; nt < 8; ++nt) {
      const int k = nt * 16 + lr;
      vdk[nt] = vd[k]; bdk[nt] = bd[k];
    }
    const int jrow = (b * LP + j) * LQ;
    #pragma unroll
    for (int rt = 0; rt < 2; ++rt) {
      #pragma unroll
      for (int q = 0; q < 4; ++q) {
        const int i = w * 32 + rt * 16 + lh * 4 + q;
        float sd = 0.f;
        #pragma unroll
        for (int nt = 0; nt < 8; ++nt)
          sd += vdk[nt] * tanh_fast(acc[rt][nt][q] + bdk[nt]);
        #pragma unroll
        for (int d = 1; d < 16; d <<= 1) sd += __shfl_xor(sd, d);
        if (lr == 0) s_d[jrow + i] = sd;
      }
    }
  } else if (bid < 1536) {
    // ---------- T-type: s_c / s_m, tile 16i x 16j
    const int sub = bid - 1024;
    const int it = sub & 7, jt = (sub >> 3) & 7, b = sub >> 6;
    float (*aq_s)[132] = (float(*)[132])(smem);
    float (*qm_s)[132] = (float(*)[132])(smem + 8448);
    float (*ap_s)[132] = (float(*)[132])(smem + 16896);
    float (*pm_s)[132] = (float(*)[132])(smem + 25344);
    float* vc_s = (float*)(smem + 33792);
    float* vm_s = (float*)(smem + 34304);
    const int lr_ = t >> 5;           // 0..7
    const int lc_ = (t & 31) * 4;     // 0..124
    #pragma unroll
    for (int rr = 0; rr < 2; ++rr) {
      const int r = lr_ + rr * 8;
      const int qrow = (b * LQ + it * 16 + r) * HID + lc_;
      const int prow = (b * LP + jt * 16 + r) * HID + lc_;
      *(float4*)&aq_s[r][lc_] = *(const float4*)&aq[qrow];
      *(float4*)&qm_s[r][lc_] = *(const float4*)&qm[qrow];
      float4 a4 = *(const float4*)&apc[prow];
      float4 c4 = *(const float4*)&bc[lc_];
      ap_s[r][lc_+0] = a4.x + c4.x; ap_s[r][lc_+1] = a4.y + c4.y;
      ap_s[r][lc_+2] = a4.z + c4.z; ap_s[r][lc_+3] = a4.w + c4.w;
      float4 p4 = *(const float4*)&pm[prow];
      float4 m4 = *(const float4*)&bm[lc_];
      pm_s[r][lc_+0] = m4.x - p4.x; pm_s[r][lc_+1] = m4.y - p4.y;
      pm_s[r][lc_+2] = m4.z - p4.z; pm_s[r][lc_+3] = m4.w - p4.w;
    }
    if (t < 128) { vc_s[t] = vc[t]; vm_s[t] = vm[t]; }
    __syncthreads();
    const int i = t & 15, j = t >> 4;
    float sc = 0.f, sm = 0.f;
    #pragma unroll 4
    for (int k = 0; k < 128; k += 4) {
      float4 av = *(const float4*)&aq_s[i][k];
      float4 pv = *(const float4*)&ap_s[j][k];
      float4 qv = *(const float4*)&qm_s[i][k];
      float4 mv = *(const float4*)&pm_s[j][k];
      float4 vcv = *(const float4*)&vc_s[k];
      float4 vmv = *(const float4*)&vm_s[k];
      sc += vcv.x * tanh_fast(av.x + pv.x) + vcv.y * tanh_fast(av.y + pv.y)
          + vcv.z * tanh_fast(av.z + pv.z) + vcv.w * tanh_fast(av.w + pv.w);
      sm += vmv.x * tanh_fast(qv.x + mv.x) + vmv.y * tanh_fast(qv.y + mv.y)
          + vmv.z * tanh_fast(qv.z + mv.z) + vmv.w * tanh_fast(qv.w + mv.w);
    }
    const int orow = (b * LP + jt * 16 + j) * LQ + it * 16 + i;
    s_c[orow] = sc;
    s_m[orow] = sm;
  } else {
    // ---------- SB-type: s_b[b][j][i] = hpb[b,j,:] . hq[b,i,:]  (f32 exact)
    const int sub = bid - 1536;       // 0..127
    const int b = sub >> 4;
    const int jt = (sub & 15) >> 2, it = sub & 3;
    float (*At)[65] = (float(*)[65])(smem);
    float (*Bt)[65] = (float(*)[65])(smem + 32 * 65 * 4);
    float acc[4] = {0.f,0.f,0.f,0.f};
    const int sr = t >> 3, c0 = (t & 7) * 8;
    const int tj = t >> 5, ti = t & 31;
    for (int kk = 0; kk < 256; kk += 64) {
      #pragma unroll
      for (int e = 0; e < 8; ++e) {
        At[sr][c0 + e] = hpb[(b * LP + jt * 32 + sr) * HH + kk + c0 + e];
        Bt[sr][c0 + e] = hq [(b * LQ + it * 32 + sr) * HH + kk + c0 + e];
      }
      __syncthreads();
      #pragma unroll
      for (int k = 0; k < 64; ++k) {
        const float bv = Bt[ti][k];
        #pragma unroll
        for (int s2 = 0; s2 < 4; ++s2) acc[s2] = fmaf(At[tj + 8 * s2][k], bv, acc[s2]);
      }
      __syncthreads();
    }
    #pragma unroll
    for (int s2 = 0; s2 < 4; ++s2)
      s_b[(b * LP + jt * 32 + tj + 8 * s2) * LQ + it * 32 + ti] = acc[s2];
  }
}

// ---------------- Kernel C: softmax over i (per (b,j,attn) column) + attend via MFMA ----------------
__global__ __launch_bounds__(256) void kernelC(
    const float* __restrict__ s_c, const float* __restrict__ s_d, const float* __restrict__ s_m,
    const float* __restrict__ s_b, const float* __restrict__ mask_hq, const float* __restrict__ mask_hp,
    const ushort_t* __restrict__ hqT_bf, float* __restrict__ out)
{
  const int b = blockIdx.y, j0 = blockIdx.x * 4;
  const int t = threadIdx.x;
  const int lane = t & 63, w = t >> 6;
  const int lr = lane & 15, lh = lane >> 4;
  __shared__ __align__(16) ushort_t a_s[16 * 128];   // bf16 softmax weights [c][i], c = attn*4+jj
  const int c = w * 4 + lh;
  const int attn = c >> 2, jj = c & 3;
  const float* sbase = (attn == 0) ? s_c : (attn == 1) ? s_d : (attn == 2) ? s_m : s_b;
  const int j = j0 + jj;
  const float mp = mask_hp[b * LP + j];
  float v[8];
  #pragma unroll
  for (int e = 0; e < 8; ++e) {
    const int i = e * 16 + lr;
    float sv = sbase[(b * LP + j) * LQ + i];
    float mq = mask_hq[b * LQ + i];
    if (mq * mp == 0.f) sv -= 10000.f;
    v[e] = sv;
  }
  float m = v[0];
  #pragma unroll
  for (int e = 1; e < 8; ++e) m = fmaxf(m, v[e]);
  #pragma unroll
  for (int d = 1; d < 16; d <<= 1) m = fmaxf(m, __shfl_xor(m, d));
  float sum = 0.f;
  #pragma unroll
  for (int e = 0; e < 8; ++e) { v[e] = __expf(v[e] - m); sum += v[e]; }
  #pragma unroll
  for (int d = 1; d < 16; d <<= 1) sum += __shfl_xor(sum, d);
  const float rs = __fdividef(1.f, sum);
  #pragma unroll
  for (int e = 0; e < 8; ++e) a_s[c * 128 + e * 16 + lr] = f2bf(v[e] * rs);
  __syncthreads();
  // out[c][h] = sum_i a[c][i] * hq[b,i,h] ; A = a_s (M=16 c), B = hqT_bf (N=h), K=i=128
  f32x4 acc[4];
  #pragma unroll
  for (int nt = 0; nt < 4; ++nt) acc[nt] = (f32x4){0.f, 0.f, 0.f, 0.f};
  #pragma unroll
  for (int ks = 0; ks < 4; ++ks) {
    bf16x8 av = *(const bf16x8*)(a_s + lr * 128 + ks * 32 + lh * 8);
    #pragma unroll
    for (int nt = 0; nt < 4; ++nt) {
      const int h = w * 64 + nt * 16 + lr;
      bf16x8 bv = *(const bf16x8*)(hqT_bf + (b * HH + h) * LQ + ks * 32 + lh * 8);
      acc[nt] = __builtin_amdgcn_mfma_f32_16x16x32_bf16(av, bv, acc[nt], 0, 0, 0);
    }
  }
  #pragma unroll
  for (int nt = 0; nt < 4; ++nt) {
    const int h = w * 64 + nt * 16 + lr;
    #pragma unroll
    for (int q = 0; q < 4; ++q) {
      const int c2 = lh * 4 + q;
      out[(b * LP + j0 + (c2 & 3)) * (4 * HH) + (c2 >> 2) * HH + h] = acc[nt][q];
    }
  }
}

extern "C" void kernel_launch(void* const* d_in, const int* in_sizes, int n_in,
                              void* d_out, int out_size, void* d_ws, size_t ws_size,
                              hipStream_t stream) {
  const float* hq      = (const float*)d_in[0];
  const float* hp      = (const float*)d_in[1];
  const float* mask_hq = (const float*)d_in[2];
  const float* mask_hp = (const float*)d_in[3];
  const float* Wc      = (const float*)d_in[4];
  const float* bc      = (const float*)d_in[5];
  const float* vc      = (const float*)d_in[6];
  const float* Wd      = (const float*)d_in[7];
  const float* bd      = (const float*)d_in[8];
  const float* vd      = (const float*)d_in[9];
  const float* Wm      = (const float*)d_in[10];
  const float* bm      = (const float*)d_in[11];
  const float* vm      = (const float*)d_in[12];
  const float* Wb      = (const float*)d_in[13];
  const float* bb      = (const float*)d_in[14];

  float* ws = (float*)d_ws;
  float* aq    = ws + 0;        // B*LQ*HID
  float* apc   = ws + 131072;   // B*LP*HID
  float* qm    = ws + 262144;   // B*LQ*HID
  float* pm    = ws + 393216;   // B*LP*HID
  float* hpb   = ws + 524288;   // B*LP*H
  float* s_c   = ws + 786432;   // B*LP*LQ  (stored [b][j][i])
  float* s_d   = ws + 917504;
  float* s_m   = ws + 1048576;
  float* s_b   = ws + 1179648;
  ushort_t* hq_bf = (ushort_t*)(ws + 1310720);  // B*LQ*H bf16
  ushort_t* wdt   = (ushort_t*)(ws + 1441792);  // HID*H bf16 (Wd transposed)
  ushort_t* hqT   = (ushort_t*)(ws + 1458176);  // B*H*LQ bf16 (hq transposed)

  kernelA<<<768, 256, 0, stream>>>(hq, hp, mask_hp, Wc, Wm, Wb, bb, Wd,
                                   aq, apc, qm, pm, hpb, hq_bf, hqT, wdt);
  kernelS<<<1664, 256, 0, stream>>>(hq, hp, hpb, aq, apc, qm, pm,
                                    bc, vc, bm, vm, bd, vd, hq_bf, wdt,
                                    s_c, s_d, s_m, s_b);
  kernelC<<<dim3(32, 8), 256, 0, stream>>>(s_c, s_d, s_m, s_b, mask_hq, mask_hp, hqT, (float*)d_out);
}

// Round 16
// 66.035 us; speedup vs baseline: 1.9047x; 1.0086x over previous
//
#include <hip/hip_runtime.h>

typedef __bf16 bf16x8 __attribute__((ext_vector_type(8)));
typedef float f32x4 __attribute__((ext_vector_type(4)));
typedef unsigned short ushort8u __attribute__((ext_vector_type(8)));
typedef unsigned short ushort_t;

#define NB 8
#define LQ 128
#define LP 128
#define HH 256
#define HID 128

__device__ __forceinline__ float bf2f(unsigned short u) {
  union { unsigned int i; float f; } v; v.i = ((unsigned int)u) << 16; return v.f;
}
__device__ __forceinline__ unsigned short f2bf(float f) {
  union { float fl; unsigned int i; } v; v.fl = f;
  unsigned int r = v.i + 0x7FFFu + ((v.i >> 16) & 1u);
  return (unsigned short)(r >> 16);
}
// tanh(x) = 1 - 2/(e^{2x}+1); e^{2x} = 2^(x*2/ln2). NaN-free at +/-inf, no clamp.
__device__ __forceinline__ float tanh_fast(float x) {
  float t = __builtin_amdgcn_exp2f(x * 2.88539008178f);
  return 1.f - 2.f * __builtin_amdgcn_rcpf(t + 1.f);
}

// ---------------- Kernel A: f32 projections + bf16 copies ----------------
__global__ __launch_bounds__(256) void kernelA(
    const float* __restrict__ hq, const float* __restrict__ hp,
    const float* __restrict__ mask_hp, const float* __restrict__ Wc,
    const float* __restrict__ Wm, const float* __restrict__ Wb,
    const float* __restrict__ bb, const float* __restrict__ Wd,
    float* __restrict__ aq, float* __restrict__ apc, float* __restrict__ qm,
    float* __restrict__ pm, float* __restrict__ hpb,
    ushort_t* __restrict__ hq_bf, ushort_t* __restrict__ hqT_bf, ushort_t* __restrict__ wdt)
{
  const int blk = blockIdx.x;
  const int typ = blk >> 8;
  const int sub = blk & 255;
  const int b = sub >> 5;
  const int i0 = (sub & 31) * 4;
  const int t = threadIdx.x;
  __shared__ __align__(16) float row[4][256];
  const float* src = (typ == 0) ? hq : hp;
  #pragma unroll
  for (int r = 0; r < 4; ++r) {
    float v = src[(b * 128 + i0 + r) * 256 + t];
    row[r][t] = v;
    if (typ == 0) {
      unsigned short bv = f2bf(v);
      hq_bf[(b * 128 + i0 + r) * 256 + t] = bv;
      hqT_bf[(b * 256 + t) * 128 + i0 + r] = bv;
    }
  }
  if (typ == 0 && sub < 128) {
    int flat = sub * 256 + t;                       // wdt[k][h] = bf16(Wd[h][k])
    wdt[flat] = f2bf(Wd[(flat & 255) * 128 + (flat >> 8)]);
  }
  __syncthreads();
  float acc[4] = {0.f,0.f,0.f,0.f};
  if (typ == 2) {
    const float* Wp = Wb + t;
    #pragma unroll 4
    for (int h = 0; h < 256; h += 4) {
      float w0 = Wp[(h+0)*256], w1 = Wp[(h+1)*256], w2 = Wp[(h+2)*256], w3 = Wp[(h+3)*256];
      #pragma unroll
      for (int r = 0; r < 4; ++r) {
        const float4 rv = *(const float4*)&row[r][h];
        acc[r] = fmaf(rv.x, w0, fmaf(rv.y, w1, fmaf(rv.z, w2, fmaf(rv.w, w3, acc[r]))));
      }
    }
    float bias = bb[t];
    #pragma unroll
    for (int r = 0; r < 4; ++r) {
      float mk = mask_hp[b * 128 + i0 + r];
      hpb[(b * 128 + i0 + r) * 256 + t] = (acc[r] + bias) * mk;
    }
  } else {
    const int c = t & 127;
    const float* Wp;
    float* outp;
    if (typ == 0) { Wp = (t < 128) ? (Wc + c) : (Wm + c);        outp = (t < 128) ? aq  : qm; }
    else          { Wp = (t < 128) ? (Wc + 32768 + c) : (Wm + c); outp = (t < 128) ? apc : pm; }
    #pragma unroll 4
    for (int h = 0; h < 256; h += 4) {
      float w0 = Wp[(h+0)*128], w1 = Wp[(h+1)*128], w2 = Wp[(h+2)*128], w3 = Wp[(h+3)*128];
      #pragma unroll
      for (int r = 0; r < 4; ++r) {
        const float4 rv = *(const float4*)&row[r][h];
        acc[r] = fmaf(rv.x, w0, fmaf(rv.y, w1, fmaf(rv.z, w2, fmaf(rv.w, w3, acc[r]))));
      }
    }
    #pragma unroll
    for (int r = 0; r < 4; ++r)
      outp[(b * 128 + i0 + r) * 128 + c] = acc[r];
  }
}

// ---------------- Kernel S: all four score matrices, block-typed ----------------
// bid < 1024 : B-type  -> s_d via MFMA  (j = bid&127, b = bid>>7)
// bid < 1536 : T-type  -> s_c, s_m tanh tiles
// else       : SB-type -> s_b f32 GEMM
__global__ __launch_bounds__(256, 2) void kernelS(
    const float* __restrict__ hq, const float* __restrict__ hp, const float* __restrict__ hpb,
    const float* __restrict__ aq, const float* __restrict__ apc,
    const float* __restrict__ qm, const float* __restrict__ pm,
    const float* __restrict__ bc, const float* __restrict__ vc,
    const float* __restrict__ bm, const float* __restrict__ vm,
    const float* __restrict__ bd, const float* __restrict__ vd,
    const ushort_t* __restrict__ hq_bf, const ushort_t* __restrict__ wdt,
    float* __restrict__ s_c, float* __restrict__ s_d,
    float* __restrict__ s_m, float* __restrict__ s_b)
{
  __shared__ __align__(16) char smem[65536];
  const int bid = blockIdx.x;
  const int t = threadIdx.x;

  if (bid < 1024) {
    // ---------- B-type: s_d[b][j][i] = sum_k vd[k] tanh( (hq @ diag(hp_j) @ Wd)[i,k] + bd[k] )
    ushort_t* X = (ushort_t*)smem;   // 64KB bf16 [k 0..127][h 0..255], XOR-swizzled
    const int j = bid & 127, b = bid >> 7;
    const int lane = t & 63, w = t >> 6;
    const int lr = lane & 15, lh = lane >> 4;
    const int h0 = (t * 8) & 255;
    const int kbase = t >> 5;
    // --- prefetch A row-pair into registers (64 VGPR): rows w*32+lr, w*32+16+lr
    const ushort_t* Ab = hq_bf + (b * LQ) * HH;
    const ushort_t* r0 = Ab + (w * 32 + lr) * HH;
    const ushort_t* r1 = Ab + (w * 32 + 16 + lr) * HH;
    bf16x8 areg0[8], areg1[8];
    #pragma unroll
    for (int s = 0; s < 8; ++s) {
      areg0[s] = *(const bf16x8*)(r0 + s * 32 + lh * 8);
      areg1[s] = *(const bf16x8*)(r1 + s * 32 + lh * 8);
    }
    // --- hp slice for this thread's h0
    const float* hprow = hp + (b * LP + j) * HH + h0;
    float hpv[8];
    {
      float4 h4a = *(const float4*)(hprow);
      float4 h4b = *(const float4*)(hprow + 4);
      hpv[0]=h4a.x; hpv[1]=h4a.y; hpv[2]=h4a.z; hpv[3]=h4a.w;
      hpv[4]=h4b.x; hpv[5]=h4b.y; hpv[6]=h4b.z; hpv[7]=h4b.w;
    }
    // --- build full X: X[k][h] = bf16( wdt[k][h] * hp[b,j,h] ), k = rep*8+kbase
    #pragma unroll
    for (int rep = 0; rep < 16; ++rep) {
      const int kl = rep * 8 + kbase;
      ushort8u wv = *(const ushort8u*)(wdt + kl * HH + h0);
      bf16x8 xv;
      #pragma unroll
      for (int e = 0; e < 8; ++e) xv[e] = (__bf16)(bf2f(wv[e]) * hpv[e]);
      const int off = (kl * 512 + h0 * 2) ^ ((kl & 7) << 4);
      *(bf16x8*)((char*)X + off) = xv;
    }
    f32x4 acc[2][8];
    #pragma unroll
    for (int a1 = 0; a1 < 2; ++a1)
      #pragma unroll
      for (int a2 = 0; a2 < 8; ++a2)
        acc[a1][a2] = (f32x4){0.f, 0.f, 0.f, 0.f};
    __syncthreads();
    // --- 128 MFMAs per wave, A from registers, B from LDS
    #pragma unroll
    for (int s = 0; s < 8; ++s) {
      #pragma unroll
      for (int nt = 0; nt < 8; ++nt) {
        const int cl = nt * 16 + lr;
        const int off = (cl * 512 + s * 64 + lh * 16) ^ ((cl & 7) << 4);
        bf16x8 bv = *(const bf16x8*)((const char*)X + off);
        acc[0][nt] = __builtin_amdgcn_mfma_f32_16x16x32_bf16(areg0[s], bv, acc[0][nt], 0, 0, 0);
        acc[1][nt] = __builtin_amdgcn_mfma_f32_16x16x32_bf16(areg1[s], bv, acc[1][nt], 0, 0, 0);
      }
    }
    // --- epilogue
    float vdk[8], bdk[8];
    #pragma unroll
    for (int nt = 0; nt < 8; ++nt) {
      const int k = nt * 16 + lr;
      vdk[nt] = vd[k]; bdk[nt] = bd[k];
    }
    const int jrow = (b * LP + j) * LQ;
    #pragma unroll
    for (int rt = 0; rt < 2; ++rt) {
      #pragma unroll
      for (int q = 0; q < 4; ++q) {
        const int i = w * 32 + rt * 16 + lh * 4 + q;
        float sd = 0.f;
        #pragma unroll
        for (int nt = 0; nt < 8; ++nt)
          sd += vdk[nt] * tanh_fast(acc[rt][nt][q] + bdk[nt]);
        #pragma unroll
        for (int d = 1; d < 16; d <<= 1) sd += __shfl_xor(sd, d);
        if (lr == 0) s_d[jrow + i] = sd;
      }
    }
  } else if (bid < 1536) {
    // ---------- T-type: s_c / s_m, tile 16i x 16j
    const int sub = bid - 1024;
    const int it = sub & 7, jt = (sub >> 3) & 7, b = sub >> 6;
    float (*aq_s)[132] = (float(*)[132])(smem);
    float (*qm_s)[132] = (float(*)[132])(smem + 8448);
    float (*ap_s)[132] = (float(*)[132])(smem + 16896);
    float (*pm_s)[132] = (float(*)[132])(smem + 25344);
    float* vc_s = (float*)(smem + 33792);
    float* vm_s = (float*)(smem + 34304);
    const int lr_ = t >> 5;           // 0..7
    const int lc_ = (t & 31) * 4;     // 0..124
    #pragma unroll
    for (int rr = 0; rr < 2; ++rr) {
      const int r = lr_ + rr * 8;
      const int qrow = (b * LQ + it * 16 + r) * HID + lc_;
      const int prow = (b * LP + jt * 16 + r) * HID + lc_;
      *(float4*)&aq_s[r][lc_] = *(const float4*)&aq[qrow];
      *(float4*)&qm_s[r][lc_] = *(const float4*)&qm[qrow];
      float4 a4 = *(const float4*)&apc[prow];
      float4 c4 = *(const float4*)&bc[lc_];
      ap_s[r][lc_+0] = a4.x + c4.x; ap_s[r][lc_+1] = a4.y + c4.y;
      ap_s[r][lc_+2] = a4.z + c4.z; ap_s[r][lc_+3] = a4.w + c4.w;
      float4 p4 = *(const float4*)&pm[prow];
      float4 m4 = *(const float4*)&bm[lc_];
      pm_s[r][lc_+0] = m4.x - p4.x; pm_s[r][lc_+1] = m4.y - p4.y;
      pm_s[r][lc_+2] = m4.z - p4.z; pm_s[r][lc_+3] = m4.w - p4.w;
    }
    if (t < 128) { vc_s[t] = vc[t]; vm_s[t] = vm[t]; }
    __syncthreads();
    const int i = t & 15, j = t >> 4;
    float sc = 0.f, sm = 0.f;
    #pragma unroll 4
    for (int k = 0; k < 128; k += 4) {
      float4 av = *(const float4*)&aq_s[i][k];
      float4 pv = *(const float4*)&ap_s[j][k];
      float4 qv = *(const float4*)&qm_s[i][k];
      float4 mv = *(const float4*)&pm_s[j][k];
      float4 vcv = *(const float4*)&vc_s[k];
      float4 vmv = *(const float4*)&vm_s[k];
      sc += vcv.x * tanh_fast(av.x + pv.x) + vcv.y * tanh_fast(av.y + pv.y)
          + vcv.z * tanh_fast(av.z + pv.z) + vcv.w * tanh_fast(av.w + pv.w);
      sm += vmv.x * tanh_fast(qv.x + mv.x) + vmv.y * tanh_fast(qv.y + mv.y)
          + vmv.z * tanh_fast(qv.z + mv.z) + vmv.w * tanh_fast(qv.w + mv.w);
    }
    const int orow = (b * LP + jt * 16 + j) * LQ + it * 16 + i;
    s_c[orow] = sc;
    s_m[orow] = sm;
  } else {
    // ---------- SB-type: s_b[b][j][i] = hpb[b,j,:] . hq[b,i,:]  (f32 exact)
    const int sub = bid - 1536;       // 0..127
    const int b = sub >> 4;
    const int jt = (sub & 15) >> 2, it = sub & 3;
    float (*At)[65] = (float(*)[65])(smem);
    float (*Bt)[65] = (float(*)[65])(smem + 32 * 65 * 4);
    float acc[4] = {0.f,0.f,0.f,0.f};
    const int sr = t >> 3, c0 = (t & 7) * 8;
    const int tj = t >> 5, ti = t & 31;
    for (int kk = 0; kk < 256; kk += 64) {
      #pragma unroll
      for (int e = 0; e < 8; ++e) {
        At[sr][c0 + e] = hpb[(b * LP + jt * 32 + sr) * HH + kk + c0 + e];
        Bt[sr][c0 + e] = hq [(b * LQ + it * 32 + sr) * HH + kk + c0 + e];
      }
      __syncthreads();
      #pragma unroll
      for (int k = 0; k < 64; ++k) {
        const float bv = Bt[ti][k];
        #pragma unroll
        for (int s2 = 0; s2 < 4; ++s2) acc[s2] = fmaf(At[tj + 8 * s2][k], bv, acc[s2]);
      }
      __syncthreads();
    }
    #pragma unroll
    for (int s2 = 0; s2 < 4; ++s2)
      s_b[(b * LP + jt * 32 + tj + 8 * s2) * LQ + it * 32 + ti] = acc[s2];
  }
}

// ---------------- Kernel C: softmax over i (per (b,j,attn) column) + attend via MFMA ----------------
__global__ __launch_bounds__(256) void kernelC(
    const float* __restrict__ s_c, const float* __restrict__ s_d, const float* __restrict__ s_m,
    const float* __restrict__ s_b, const float* __restrict__ mask_hq, const float* __restrict__ mask_hp,
    const ushort_t* __restrict__ hqT_bf, float* __restrict__ out)
{
  const int b = blockIdx.y, j0 = blockIdx.x * 4;
  const int t = threadIdx.x;
  const int lane = t & 63, w = t >> 6;
  const int lr = lane & 15, lh = lane >> 4;
  __shared__ __align__(16) ushort_t a_s[16 * 128];   // bf16 softmax weights [c][i], c = attn*4+jj
  const int c = w * 4 + lh;
  const int attn = c >> 2, jj = c & 3;
  const float* sbase = (attn == 0) ? s_c : (attn == 1) ? s_d : (attn == 2) ? s_m : s_b;
  const int j = j0 + jj;
  const float mp = mask_hp[b * LP + j];
  float v[8];
  #pragma unroll
  for (int e = 0; e < 8; ++e) {
    const int i = e * 16 + lr;
    float sv = sbase[(b * LP + j) * LQ + i];
    float mq = mask_hq[b * LQ + i];
    if (mq * mp == 0.f) sv -= 10000.f;
    v[e] = sv;
  }
  float m = v[0];
  #pragma unroll
  for (int e = 1; e < 8; ++e) m = fmaxf(m, v[e]);
  #pragma unroll
  for (int d = 1; d < 16; d <<= 1) m = fmaxf(m, __shfl_xor(m, d));
  float sum = 0.f;
  #pragma unroll
  for (int e = 0; e < 8; ++e) { v[e] = __expf(v[e] - m); sum += v[e]; }
  #pragma unroll
  for (int d = 1; d < 16; d <<= 1) sum += __shfl_xor(sum, d);
  const float rs = __fdividef(1.f, sum);
  #pragma unroll
  for (int e = 0; e < 8; ++e) a_s[c * 128 + e * 16 + lr] = f2bf(v[e] * rs);
  __syncthreads();
  // out[c][h] = sum_i a[c][i] * hq[b,i,h] ; A = a_s (M=16 c), B = hqT_bf (N=h), K=i=128
  f32x4 acc[4];
  #pragma unroll
  for (int nt = 0; nt < 4; ++nt) acc[nt] = (f32x4){0.f, 0.f, 0.f, 0.f};
  #pragma unroll
  for (int ks = 0; ks < 4; ++ks) {
    bf16x8 av = *(const bf16x8*)(a_s + lr * 128 + ks * 32 + lh * 8);
    #pragma unroll
    for (int nt = 0; nt < 4; ++nt) {
      const int h = w * 64 + nt * 16 + lr;
      bf16x8 bv = *(const bf16x8*)(hqT_bf + (b * HH + h) * LQ + ks * 32 + lh * 8);
      acc[nt] = __builtin_amdgcn_mfma_f32_16x16x32_bf16(av, bv, acc[nt], 0, 0, 0);
    }
  }
  #pragma unroll
  for (int nt = 0; nt < 4; ++nt) {
    const int h = w * 64 + nt * 16 + lr;
    #pragma unroll
    for (int q = 0; q < 4; ++q) {
      const int c2 = lh * 4 + q;
      out[(b * LP + j0 + (c2 & 3)) * (4 * HH) + (c2 >> 2) * HH + h] = acc[nt][q];
    }
  }
}

extern "C" void kernel_launch(void* const* d_in, const int* in_sizes, int n_in,
                              void* d_out, int out_size, void* d_ws, size_t ws_size,
                              hipStream_t stream) {
  const float* hq      = (const float*)d_in[0];
  const float* hp      = (const float*)d_in[1];
  const float* mask_hq = (const float*)d_in[2];
  const float* mask_hp = (const float*)d_in[3];
  const float* Wc      = (const float*)d_in[4];
  const float* bc      = (const float*)d_in[5];
  const float* vc      = (const float*)d_in[6];
  const float* Wd      = (const float*)d_in[7];
  const float* bd      = (const float*)d_in[8];
  const float* vd      = (const float*)d_in[9];
  const float* Wm      = (const float*)d_in[10];
  const float* bm      = (const float*)d_in[11];
  const float* vm      = (const float*)d_in[12];
  const float* Wb      = (const float*)d_in[13];
  const float* bb      = (const float*)d_in[14];

  float* ws = (float*)d_ws;
  float* aq    = ws + 0;        // B*LQ*HID
  float* apc   = ws + 131072;   // B*LP*HID
  float* qm    = ws + 262144;   // B*LQ*HID
  float* pm    = ws + 393216;   // B*LP*HID
  float* hpb   = ws + 524288;   // B*LP*H
  float* s_c   = ws + 786432;   // B*LP*LQ  (stored [b][j][i])
  float* s_d   = ws + 917504;
  float* s_m   = ws + 1048576;
  float* s_b   = ws + 1179648;
  ushort_t* hq_bf = (ushort_t*)(ws + 1310720);  // B*LQ*H bf16
  ushort_t* wdt   = (ushort_t*)(ws + 1441792);  // HID*H bf16 (Wd transposed)
  ushort_t* hqT   = (ushort_t*)(ws + 1458176);  // B*H*LQ bf16 (hq transposed)

  kernelA<<<768, 256, 0, stream>>>(hq, hp, mask_hp, Wc, Wm, Wb, bb, Wd,
                                   aq, apc, qm, pm, hpb, hq_bf, hqT, wdt);
  kernelS<<<1664, 256, 0, stream>>>(hq, hp, hpb, aq, apc, qm, pm,
                                    bc, vc, bm, vm, bd, vd, hq_bf, wdt,
                                    s_c, s_d, s_m, s_b);
  kernelC<<<dim3(32, 8), 256, 0, stream>>>(s_c, s_d, s_m, s_b, mask_hq, mask_hp, hqT, (float*)d_out);
}

// Round 17
// 65.959 us; speedup vs baseline: 1.9069x; 1.0012x over previous
//
#include <hip/hip_runtime.h>

typedef __bf16 bf16x8 __attribute__((ext_vector_type(8)));
typedef float f32x4 __attribute__((ext_vector_type(4)));
typedef unsigned short ushort8u __attribute__((ext_vector_type(8)));
typedef unsigned short ushort_t;

#define NB 8
#define LQ 128
#define LP 128
#define HH 256
#define HID 128

__device__ __forceinline__ float bf2f(unsigned short u) {
  union { unsigned int i; float f; } v; v.i = ((unsigned int)u) << 16; return v.f;
}
__device__ __forceinline__ unsigned short f2bf(float f) {
  union { float fl; unsigned int i; } v; v.fl = f;
  unsigned int r = v.i + 0x7FFFu + ((v.i >> 16) & 1u);
  return (unsigned short)(r >> 16);
}
// tanh(x) = 1 - 2/(e^{2x}+1); e^{2x} = 2^(x*2/ln2). NaN-free at +/-inf, no clamp.
__device__ __forceinline__ float tanh_fast(float x) {
  float t = __builtin_amdgcn_exp2f(x * 2.88539008178f);
  return 1.f - 2.f * __builtin_amdgcn_rcpf(t + 1.f);
}

// ---------------- Kernel A: f32 projections + bf16 copies ----------------
__global__ __launch_bounds__(256) void kernelA(
    const float* __restrict__ hq, const float* __restrict__ hp,
    const float* __restrict__ mask_hp, const float* __restrict__ Wc,
    const float* __restrict__ Wm, const float* __restrict__ Wb,
    const float* __restrict__ bb, const float* __restrict__ Wd,
    float* __restrict__ aq, float* __restrict__ apc, float* __restrict__ qm,
    float* __restrict__ pm, float* __restrict__ hpb,
    ushort_t* __restrict__ hq_bf, ushort_t* __restrict__ hqT_bf, ushort_t* __restrict__ wdt)
{
  const int blk = blockIdx.x;
  const int typ = blk >> 8;
  const int sub = blk & 255;
  const int b = sub >> 5;
  const int i0 = (sub & 31) * 4;
  const int t = threadIdx.x;
  __shared__ __align__(16) float row[4][256];
  const float* src = (typ == 0) ? hq : hp;
  #pragma unroll
  for (int r = 0; r < 4; ++r) {
    float v = src[(b * 128 + i0 + r) * 256 + t];
    row[r][t] = v;
    if (typ == 0) {
      unsigned short bv = f2bf(v);
      hq_bf[(b * 128 + i0 + r) * 256 + t] = bv;
      hqT_bf[(b * 256 + t) * 128 + i0 + r] = bv;
    }
  }
  if (typ == 0 && sub < 128) {
    int flat = sub * 256 + t;                       // wdt[k][h] = bf16(Wd[h][k])
    wdt[flat] = f2bf(Wd[(flat & 255) * 128 + (flat >> 8)]);
  }
  __syncthreads();
  float acc[4] = {0.f,0.f,0.f,0.f};
  if (typ == 2) {
    const float* Wp = Wb + t;
    #pragma unroll 4
    for (int h = 0; h < 256; h += 4) {
      float w0 = Wp[(h+0)*256], w1 = Wp[(h+1)*256], w2 = Wp[(h+2)*256], w3 = Wp[(h+3)*256];
      #pragma unroll
      for (int r = 0; r < 4; ++r) {
        const float4 rv = *(const float4*)&row[r][h];
        acc[r] = fmaf(rv.x, w0, fmaf(rv.y, w1, fmaf(rv.z, w2, fmaf(rv.w, w3, acc[r]))));
      }
    }
    float bias = bb[t];
    #pragma unroll
    for (int r = 0; r < 4; ++r) {
      float mk = mask_hp[b * 128 + i0 + r];
      hpb[(b * 128 + i0 + r) * 256 + t] = (acc[r] + bias) * mk;
    }
  } else {
    const int c = t & 127;
    const float* Wp;
    float* outp;
    if (typ == 0) { Wp = (t < 128) ? (Wc + c) : (Wm + c);        outp = (t < 128) ? aq  : qm; }
    else          { Wp = (t < 128) ? (Wc + 32768 + c) : (Wm + c); outp = (t < 128) ? apc : pm; }
    #pragma unroll 4
    for (int h = 0; h < 256; h += 4) {
      float w0 = Wp[(h+0)*128], w1 = Wp[(h+1)*128], w2 = Wp[(h+2)*128], w3 = Wp[(h+3)*128];
      #pragma unroll
      for (int r = 0; r < 4; ++r) {
        const float4 rv = *(const float4*)&row[r][h];
        acc[r] = fmaf(rv.x, w0, fmaf(rv.y, w1, fmaf(rv.z, w2, fmaf(rv.w, w3, acc[r]))));
      }
    }
    #pragma unroll
    for (int r = 0; r < 4; ++r)
      outp[(b * 128 + i0 + r) * 128 + c] = acc[r];
  }
}

// ---------------- Kernel S: all four score matrices, block-typed ----------------
// bid < 1024 : B-type  -> s_d via MFMA  (j = bid&127, b = bid>>7)
// bid < 1536 : T-type  -> s_c, s_m tanh tiles
// else       : SB-type -> s_b f32 GEMM
__global__ __launch_bounds__(256, 2) void kernelS(
    const float* __restrict__ hq, const float* __restrict__ hp, const float* __restrict__ hpb,
    const float* __restrict__ aq, const float* __restrict__ apc,
    const float* __restrict__ qm, const float* __restrict__ pm,
    const float* __restrict__ bc, const float* __restrict__ vc,
    const float* __restrict__ bm, const float* __restrict__ vm,
    const float* __restrict__ bd, const float* __restrict__ vd,
    const ushort_t* __restrict__ hq_bf, const ushort_t* __restrict__ wdt,
    float* __restrict__ s_c, float* __restrict__ s_d,
    float* __restrict__ s_m, float* __restrict__ s_b)
{
  __shared__ __align__(16) char smem[65536];
  const int bid = blockIdx.x;
  const int t = threadIdx.x;

  if (bid < 1024) {
    // ---------- B-type: s_d[b][j][i] = sum_k vd[k] tanh( (hq @ diag(hp_j) @ Wd)[i,k] + bd[k] )
    ushort_t* X = (ushort_t*)smem;   // 64KB bf16 [k 0..127][h 0..255], XOR-swizzled
    const int j = bid & 127, b = bid >> 7;
    const int lane = t & 63, w = t >> 6;
    const int lr = lane & 15, lh = lane >> 4;
    const int h0 = (t * 8) & 255;
    const int kbase = t >> 5;
    // --- prefetch A row-pair into registers (64 VGPR): rows w*32+lr, w*32+16+lr
    const ushort_t* Ab = hq_bf + (b * LQ) * HH;
    const ushort_t* r0 = Ab + (w * 32 + lr) * HH;
    const ushort_t* r1 = Ab + (w * 32 + 16 + lr) * HH;
    bf16x8 areg0[8], areg1[8];
    #pragma unroll
    for (int s = 0; s < 8; ++s) {
      areg0[s] = *(const bf16x8*)(r0 + s * 32 + lh * 8);
      areg1[s] = *(const bf16x8*)(r1 + s * 32 + lh * 8);
    }
    // --- hp slice for this thread's h0
    const float* hprow = hp + (b * LP + j) * HH + h0;
    float hpv[8];
    {
      float4 h4a = *(const float4*)(hprow);
      float4 h4b = *(const float4*)(hprow + 4);
      hpv[0]=h4a.x; hpv[1]=h4a.y; hpv[2]=h4a.z; hpv[3]=h4a.w;
      hpv[4]=h4b.x; hpv[5]=h4b.y; hpv[6]=h4b.z; hpv[7]=h4b.w;
    }
    // --- build full X: X[k][h] = bf16( wdt[k][h] * hp[b,j,h] ), k = rep*8+kbase
    #pragma unroll
    for (int rep = 0; rep < 16; ++rep) {
      const int kl = rep * 8 + kbase;
      ushort8u wv = *(const ushort8u*)(wdt + kl * HH + h0);
      bf16x8 xv;
      #pragma unroll
      for (int e = 0; e < 8; ++e) xv[e] = (__bf16)(bf2f(wv[e]) * hpv[e]);
      const int off = (kl * 512 + h0 * 2) ^ ((kl & 7) << 4);
      *(bf16x8*)((char*)X + off) = xv;
    }
    f32x4 acc[2][8];
    #pragma unroll
    for (int a1 = 0; a1 < 2; ++a1)
      #pragma unroll
      for (int a2 = 0; a2 < 8; ++a2)
        acc[a1][a2] = (f32x4){0.f, 0.f, 0.f, 0.f};
    __syncthreads();
    // --- 128 MFMAs per wave, A from registers, B from LDS
    #pragma unroll
    for (int s = 0; s < 8; ++s) {
      #pragma unroll
      for (int nt = 0; nt < 8; ++nt) {
        const int cl = nt * 16 + lr;
        const int off = (cl * 512 + s * 64 + lh * 16) ^ ((cl & 7) << 4);
        bf16x8 bv = *(const bf16x8*)((const char*)X + off);
        acc[0][nt] = __builtin_amdgcn_mfma_f32_16x16x32_bf16(areg0[s], bv, acc[0][nt], 0, 0, 0);
        acc[1][nt] = __builtin_amdgcn_mfma_f32_16x16x32_bf16(areg1[s], bv, acc[1][nt], 0, 0, 0);
      }
    }
    // --- epilogue
    float vdk[8], bdk[8];
    #pragma unroll
    for (int nt = 0; nt < 8; ++nt) {
      const int k = nt * 16 + lr;
      vdk[nt] = vd[k]; bdk[nt] = bd[k];
    }
    const int jrow = (b * LP + j) * LQ;
    #pragma unroll
    for (int rt = 0; rt < 2; ++rt) {
      #pragma unroll
      for (int q = 0; q < 4; ++q) {
        const int i = w * 32 + rt * 16 + lh * 4 + q;
        float sd = 0.f;
        #pragma unroll
        for (int nt = 0; nt < 8; ++nt)
          sd += vdk[nt] * tanh_fast(acc[rt][nt][q] + bdk[nt]);
        #pragma unroll
        for (int d = 1; d < 16; d <<= 1) sd += __shfl_xor(sd, d);
        if (lr == 0) s_d[jrow + i] = sd;
      }
    }
  } else if (bid < 1536) {
    // ---------- T-type: s_c / s_m, tile 16i x 16j
    const int sub = bid - 1024;
    const int it = sub & 7, jt = (sub >> 3) & 7, b = sub >> 6;
    float (*aq_s)[132] = (float(*)[132])(smem);
    float (*qm_s)[132] = (float(*)[132])(smem + 8448);
    float (*ap_s)[132] = (float(*)[132])(smem + 16896);
    float (*pm_s)[132] = (float(*)[132])(smem + 25344);
    float* vc_s = (float*)(smem + 33792);
    float* vm_s = (float*)(smem + 34304);
    const int lr_ = t >> 5;           // 0..7
    const int lc_ = (t & 31) * 4;     // 0..124
    #pragma unroll
    for (int rr = 0; rr < 2; ++rr) {
      const int r = lr_ + rr * 8;
      const int qrow = (b * LQ + it * 16 + r) * HID + lc_;
      const int prow = (b * LP + jt * 16 + r) * HID + lc_;
      *(float4*)&aq_s[r][lc_] = *(const float4*)&aq[qrow];
      *(float4*)&qm_s[r][lc_] = *(const float4*)&qm[qrow];
      float4 a4 = *(const float4*)&apc[prow];
      float4 c4 = *(const float4*)&bc[lc_];
      ap_s[r][lc_+0] = a4.x + c4.x; ap_s[r][lc_+1] = a4.y + c4.y;
      ap_s[r][lc_+2] = a4.z + c4.z; ap_s[r][lc_+3] = a4.w + c4.w;
      float4 p4 = *(const float4*)&pm[prow];
      float4 m4 = *(const float4*)&bm[lc_];
      pm_s[r][lc_+0] = m4.x - p4.x; pm_s[r][lc_+1] = m4.y - p4.y;
      pm_s[r][lc_+2] = m4.z - p4.z; pm_s[r][lc_+3] = m4.w - p4.w;
    }
    if (t < 128) { vc_s[t] = vc[t]; vm_s[t] = vm[t]; }
    __syncthreads();
    const int i = t & 15, j = t >> 4;
    float sc = 0.f, sm = 0.f;
    #pragma unroll 4
    for (int k = 0; k < 128; k += 4) {
      float4 av = *(const float4*)&aq_s[i][k];
      float4 pv = *(const float4*)&ap_s[j][k];
      float4 qv = *(const float4*)&qm_s[i][k];
      float4 mv = *(const float4*)&pm_s[j][k];
      float4 vcv = *(const float4*)&vc_s[k];
      float4 vmv = *(const float4*)&vm_s[k];
      sc += vcv.x * tanh_fast(av.x + pv.x) + vcv.y * tanh_fast(av.y + pv.y)
          + vcv.z * tanh_fast(av.z + pv.z) + vcv.w * tanh_fast(av.w + pv.w);
      sm += vmv.x * tanh_fast(qv.x + mv.x) + vmv.y * tanh_fast(qv.y + mv.y)
          + vmv.z * tanh_fast(qv.z + mv.z) + vmv.w * tanh_fast(qv.w + mv.w);
    }
    const int orow = (b * LP + jt * 16 + j) * LQ + it * 16 + i;
    s_c[orow] = sc;
    s_m[orow] = sm;
  } else {
    // ---------- SB-type: s_b[b][j][i] = hpb[b,j,:] . hq[b,i,:]  (f32 exact)
    const int sub = bid - 1536;       // 0..127
    const int b = sub >> 4;
    const int jt = (sub & 15) >> 2, it = sub & 3;
    float (*At)[65] = (float(*)[65])(smem);
    float (*Bt)[65] = (float(*)[65])(smem + 32 * 65 * 4);
    float acc[4] = {0.f,0.f,0.f,0.f};
    const int sr = t >> 3, c0 = (t & 7) * 8;
    const int tj = t >> 5, ti = t & 31;
    for (int kk = 0; kk < 256; kk += 64) {
      #pragma unroll
      for (int e = 0; e < 8; ++e) {
        At[sr][c0 + e] = hpb[(b * LP + jt * 32 + sr) * HH + kk + c0 + e];
        Bt[sr][c0 + e] = hq [(b * LQ + it * 32 + sr) * HH + kk + c0 + e];
      }
      __syncthreads();
      #pragma unroll
      for (int k = 0; k < 64; ++k) {
        const float bv = Bt[ti][k];
        #pragma unroll
        for (int s2 = 0; s2 < 4; ++s2) acc[s2] = fmaf(At[tj + 8 * s2][k], bv, acc[s2]);
      }
      __syncthreads();
    }
    #pragma unroll
    for (int s2 = 0; s2 < 4; ++s2)
      s_b[(b * LP + jt * 32 + tj + 8 * s2) * LQ + it * 32 + ti] = acc[s2];
  }
}

// ---------------- Kernel C: softmax over i (per (b,j,attn) column) + attend via MFMA ----------------
__global__ __launch_bounds__(256) void kernelC(
    const float* __restrict__ s_c, const float* __restrict__ s_d, const float* __restrict__ s_m,
    const float* __restrict__ s_b, const float* __restrict__ mask_hq, const float* __restrict__ mask_hp,
    const ushort_t* __restrict__ hqT_bf, float* __restrict__ out)
{
  const int b = blockIdx.y, j0 = blockIdx.x * 4;
  const int t = threadIdx.x;
  const int lane = t & 63, w = t >> 6;
  const int lr = lane & 15, lh = lane >> 4;
  __shared__ __align__(16) ushort_t a_s[16 * 128];   // bf16 softmax weights [c][i], c = attn*4+jj
  const int c = w * 4 + lh;
  const int attn = c >> 2, jj = c & 3;
  const float* sbase = (attn == 0) ? s_c : (attn == 1) ? s_d : (attn == 2) ? s_m : s_b;
  const int j = j0 + jj;
  const float mp = mask_hp[b * LP + j];
  float v[8];
  #pragma unroll
  for (int e = 0; e < 8; ++e) {
    const int i = e * 16 + lr;
    float sv = sbase[(b * LP + j) * LQ + i];
    float mq = mask_hq[b * LQ + i];
    if (mq * mp == 0.f) sv -= 10000.f;
    v[e] = sv;
  }
  float m = v[0];
  #pragma unroll
  for (int e = 1; e < 8; ++e) m = fmaxf(m, v[e]);
  #pragma unroll
  for (int d = 1; d < 16; d <<= 1) m = fmaxf(m, __shfl_xor(m, d));
  float sum = 0.f;
  #pragma unroll
  for (int e = 0; e < 8; ++e) { v[e] = __expf(v[e] - m); sum += v[e]; }
  #pragma unroll
  for (int d = 1; d < 16; d <<= 1) sum += __shfl_xor(sum, d);
  const float rs = __fdividef(1.f, sum);
  #pragma unroll
  for (int e = 0; e < 8; ++e) a_s[c * 128 + e * 16 + lr] = f2bf(v[e] * rs);
  __syncthreads();
  // out[c][h] = sum_i a[c][i] * hq[b,i,h] ; A = a_s (M=16 c), B = hqT_bf (N=h), K=i=128
  f32x4 acc[4];
  #pragma unroll
  for (int nt = 0; nt < 4; ++nt) acc[nt] = (f32x4){0.f, 0.f, 0.f, 0.f};
  #pragma unroll
  for (int ks = 0; ks < 4; ++ks) {
    bf16x8 av = *(const bf16x8*)(a_s + lr * 128 + ks * 32 + lh * 8);
    #pragma unroll
    for (int nt = 0; nt < 4; ++nt) {
      const int h = w * 64 + nt * 16 + lr;
      bf16x8 bv = *(const bf16x8*)(hqT_bf + (b * HH + h) * LQ + ks * 32 + lh * 8);
      acc[nt] = __builtin_amdgcn_mfma_f32_16x16x32_bf16(av, bv, acc[nt], 0, 0, 0);
    }
  }
  #pragma unroll
  for (int nt = 0; nt < 4; ++nt) {
    const int h = w * 64 + nt * 16 + lr;
    #pragma unroll
    for (int q = 0; q < 4; ++q) {
      const int c2 = lh * 4 + q;
      out[(b * LP + j0 + (c2 & 3)) * (4 * HH) + (c2 >> 2) * HH + h] = acc[nt][q];
    }
  }
}

extern "C" void kernel_launch(void* const* d_in, const int* in_sizes, int n_in,
                              void* d_out, int out_size, void* d_ws, size_t ws_size,
                              hipStream_t stream) {
  const float* hq      = (const float*)d_in[0];
  const float* hp      = (const float*)d_in[1];
  const float* mask_hq = (const float*)d_in[2];
  const float* mask_hp = (const float*)d_in[3];
  const float* Wc      = (const float*)d_in[4];
  const float* bc      = (const float*)d_in[5];
  const float* vc      = (const float*)d_in[6];
  const float* Wd      = (const float*)d_in[7];
  const float* bd      = (const float*)d_in[8];
  const float* vd      = (const float*)d_in[9];
  const float* Wm      = (const float*)d_in[10];
  const float* bm      = (const float*)d_in[11];
  const float* vm      = (const float*)d_in[12];
  const float* Wb      = (const float*)d_in[13];
  const float* bb      = (const float*)d_in[14];

  float* ws = (float*)d_ws;
  float* aq    = ws + 0;        // B*LQ*HID
  float* apc   = ws + 131072;   // B*LP*HID
  float* qm    = ws + 262144;   // B*LQ*HID
  float* pm    = ws + 393216;   // B*LP*HID
  float* hpb   = ws + 524288;   // B*LP*H
  float* s_c   = ws + 786432;   // B*LP*LQ  (stored [b][j][i])
  float* s_d   = ws + 917504;
  float* s_m   = ws + 1048576;
  float* s_b   = ws + 1179648;
  ushort_t* hq_bf = (ushort_t*)(ws + 1310720);  // B*LQ*H bf16
  ushort_t* wdt   = (ushort_t*)(ws + 1441792);  // HID*H bf16 (Wd transposed)
  ushort_t* hqT   = (ushort_t*)(ws + 1458176);  // B*H*LQ bf16 (hq transposed)

  kernelA<<<768, 256, 0, stream>>>(hq, hp, mask_hp, Wc, Wm, Wb, bb, Wd,
                                   aq, apc, qm, pm, hpb, hq_bf, hqT, wdt);
  kernelS<<<1664, 256, 0, stream>>>(hq, hp, hpb, aq, apc, qm, pm,
                                    bc, vc, bm, vm, bd, vd, hq_bf, wdt,
                                    s_c, s_d, s_m, s_b);
  kernelC<<<dim3(32, 8), 256, 0, stream>>>(s_c, s_d, s_m, s_b, mask_hq, mask_hp, hqT, (float*)d_out);
}